// Round 15
// baseline (106.170 us; speedup 1.0000x reference)
//
#include <hip/hip_runtime.h>
#include <math.h>

// Problem constants (match reference setup_inputs)
#define B_N   8192      // samples
#define Z_D   128       // feature dim
#define P_N   93        // proxies
#define NCLS  62        // classes
#define A_N   2730      // anchors: arange(0, 8189, 3)
#define BCAP  256       // class-bucket capacity (max expected ~180)
#define GT_S  96        // GT row stride
#define NPART 683       // ceil(A_N / 4) = kB2 grid; 683 = 16*42 + 11
#define TWO_EPS   2e-6f
#define ZEPS2     (128.0f * 1e-6f * 1e-6f)

// Relaxed agent-scope ops: coherence-point execution, no cache maintenance
// (R5/R6/R10/R11-validated). Hierarchical counters keep RMW chains <=43 deep.
#define AT_LD(p)      __hip_atomic_load((p), __ATOMIC_RELAXED, __HIP_MEMORY_SCOPE_AGENT)
#define AT_ST(p, v)   __hip_atomic_store((p), (v), __ATOMIC_RELAXED, __HIP_MEMORY_SCOPE_AGENT)
#define AT_ADDU(p, v) __hip_atomic_fetch_add((p), (v), __ATOMIC_RELAXED, __HIP_MEMORY_SCOPE_AGENT)

__device__ __forceinline__ float wave_sum(float v) {
#pragma unroll
  for (int off = 1; off < 64; off <<= 1) v += __shfl_xor(v, off, 64);
  return v;
}
__device__ __forceinline__ float wave_min(float v) {
#pragma unroll
  for (int off = 1; off < 64; off <<= 1) v = fminf(v, __shfl_xor(v, off, 64));
  return v;
}

// --- kA: EXACT R12-benched body (81.4 us config: 318 blocks x 512 thr,
// 1 row/thread, LDS pre-scaled proxy tile). Launched 3x this round to
// measure T_kA from the total delta (kA is idempotent; bucket order differs
// between runs but kB2's smallest-j tie-break is order-invariant). ----------
__global__ __launch_bounds__(512) void kA(
    const float* __restrict__ z, const int* __restrict__ y_idx,
    const float* __restrict__ prox, const int* __restrict__ y_map,
    float* __restrict__ pp, float* __restrict__ sp,
    float* __restrict__ zz, float* __restrict__ sz, float* __restrict__ w,
    int* __restrict__ cnt, int* __restrict__ bkt, float* __restrict__ GT,
    unsigned int* __restrict__ ctr) {
  __shared__ float linv[6];
  __shared__ float pt[6 * Z_D];            // pre-scaled proxy tile (3 KB)
  __shared__ int lcnt;
  const int b = blockIdx.x, tid = threadIdx.x;
  const int lane = tid & 63, wv = tid >> 6;

  if (b == 0 && tid < 17) ctr[tid * 32] = 0u;  // visible to kB2 via boundary

  if (b < 256) {
    // --- P1: 16 j-chunks x 512 rows (1 row/thread), 16 k-tiles.
    // Tiles 0..14: 6 proxies; tile 15: proxies 90..92 + z row stats + w.
    const int jch = b & 15, kt = b >> 4, k0 = kt * 6;
    const int nk = (kt == 15) ? 3 : 6;
    const int j = jch * 512 + tid;
    const float* __restrict__ zrow = z + (size_t)j * Z_D;
    if (wv < nk) {                         // per-proxy norm via wave reduce
      const int k = k0 + wv;
      const float a = prox[k * Z_D + lane];
      const float c = prox[k * Z_D + 64 + lane];
      const float s = wave_sum(a + c);
      const float q = wave_sum(a * a + c * c);
      const float inv = 1.0f / fmaxf(sqrtf(q), 1e-12f);
      if (lane == 0) {
        linv[wv] = inv;
        if (jch == 0) { pp[k] = q * inv * inv; sp[k] = s * inv; }
      }
    }
    __syncthreads();
    // stage tile into LDS, pre-scaled by inv-norm (t>>5 = row, 32 f4/row)
    {
      const int nf = nk * 32;
      const float4* __restrict__ src = (const float4*)(prox + (size_t)k0 * Z_D);
      for (int t = tid; t < nf; t += 512) {
        const float iv = linv[t >> 5];
        const float4 v = src[t];
        ((float4*)pt)[t] = make_float4(v.x * iv, v.y * iv, v.z * iv, v.w * iv);
      }
    }
    __syncthreads();
    if (kt < 15) {
      float a0 = 0, a1 = 0, a2 = 0, a3 = 0, a4 = 0, a5 = 0;
#pragma unroll 8
      for (int i4 = 0; i4 < Z_D; i4 += 4) {
        const float4 zv = *(const float4*)(zrow + i4);
        const int f = i4 >> 2;
        const float4 q0 = ((const float4*)pt)[0 * 32 + f];  // LDS broadcast
        const float4 q1 = ((const float4*)pt)[1 * 32 + f];
        const float4 q2 = ((const float4*)pt)[2 * 32 + f];
        const float4 q3 = ((const float4*)pt)[3 * 32 + f];
        const float4 q4 = ((const float4*)pt)[4 * 32 + f];
        const float4 q5 = ((const float4*)pt)[5 * 32 + f];
        a0 += zv.x * q0.x + zv.y * q0.y + zv.z * q0.z + zv.w * q0.w;
        a1 += zv.x * q1.x + zv.y * q1.y + zv.z * q1.z + zv.w * q1.w;
        a2 += zv.x * q2.x + zv.y * q2.y + zv.z * q2.z + zv.w * q2.w;
        a3 += zv.x * q3.x + zv.y * q3.y + zv.z * q3.z + zv.w * q3.w;
        a4 += zv.x * q4.x + zv.y * q4.y + zv.z * q4.z + zv.w * q4.w;
        a5 += zv.x * q5.x + zv.y * q5.y + zv.z * q5.z + zv.w * q5.w;
      }
      float* g = GT + (size_t)j * GT_S + k0;       // k0 even -> 8B aligned
      *(float2*)(g + 0) = make_float2(a0, a1);
      *(float2*)(g + 2) = make_float2(a2, a3);
      *(float2*)(g + 4) = make_float2(a4, a5);
    } else {
      float a0 = 0, a1 = 0, a2 = 0, zs = 0, zq = 0;
#pragma unroll 8
      for (int i4 = 0; i4 < Z_D; i4 += 4) {
        const float4 zv = *(const float4*)(zrow + i4);
        const int f = i4 >> 2;
        const float4 q0 = ((const float4*)pt)[0 * 32 + f];
        const float4 q1 = ((const float4*)pt)[1 * 32 + f];
        const float4 q2 = ((const float4*)pt)[2 * 32 + f];
        zs += zv.x + zv.y + zv.z + zv.w;
        zq += zv.x * zv.x + zv.y * zv.y + zv.z * zv.z + zv.w * zv.w;
        a0 += zv.x * q0.x + zv.y * q0.y + zv.z * q0.z + zv.w * q0.w;
        a1 += zv.x * q1.x + zv.y * q1.y + zv.z * q1.z + zv.w * q1.w;
        a2 += zv.x * q2.x + zv.y * q2.y + zv.z * q2.z + zv.w * q2.w;
      }
      float* g = GT + (size_t)j * GT_S + 90;       // 90 even -> 8B aligned
      *(float2*)(g) = make_float2(a0, a1);
      g[2] = a2;
      zz[j] = zq;
      sz[j] = zs;
      w[j] = zq - TWO_EPS * zs;            // per-j part of pdist(prox, z)
    }
  } else {
    // --- P0: class c = b-256 compacts its sample indices (y_map unique).
    const int c = b - 256;
    if (tid == 0) lcnt = 0;
    __syncthreads();
    const int ym = y_map[c];
    for (int j = tid; j < B_N; j += 512) {
      if (y_idx[j] == ym) {
        const int pos = atomicAdd(&lcnt, 1);     // LDS atomic
        if (pos < BCAP) bkt[c * BCAP + pos] = j;
      }
    }
    __syncthreads();
    if (tid == 0) cnt[c] = min(lcnt, BCAP);
  }
}

// --- kB2: EXACT R12-benched body (one wave per anchor; hierarchical
// finalize). Safe under repeated kA runs (order-invariant reduce). ----------
__global__ __launch_bounds__(256) void kB2(
    const int* __restrict__ y_idx, const int* __restrict__ y_map,
    const float* __restrict__ pp, const float* __restrict__ sp,
    const float* __restrict__ zz, const float* __restrict__ sz,
    const float* __restrict__ w,
    const int* __restrict__ cnt, const int* __restrict__ bkt,
    const float* __restrict__ GT, float* partial, unsigned int* ctr,
    float* __restrict__ out) {
  __shared__ float lpp[P_N], lsp[P_N];
  __shared__ int lymap[NCLS];
  __shared__ float part[4];
  const int b = blockIdx.x;
  const int tid = threadIdx.x, lane = tid & 63, wv = tid >> 6;
  if (tid < P_N) { lpp[tid] = pp[tid]; lsp[tid] = sp[tid]; }
  if (tid < NCLS) lymap[tid] = y_map[tid];
  __syncthreads();

  const int wid = b * 4 + wv;
  float loss = 0.0f;
  if (wid < A_N) {
    const int i = 3 * wid;
    const int yi = y_idx[i];
    const unsigned long long mm = __ballot(lane < NCLS && lymap[lane] == yi);
    const int cls = __ffsll(mm) - 1;       // unique match (y_map unique)
    const float zzi = zz[i], szi = sz[i];
    const int kB = lane + 64;

    // step a: nearest proxy (argmin, first-index tie-break)
    const float* __restrict__ GTi = GT + (size_t)i * GT_S;
    float v1 = fmaxf(zzi + lpp[lane] - 2.0f * GTi[lane] +
                     TWO_EPS * (szi - lsp[lane]) + ZEPS2, 0.0f);
    int i1 = lane;
    if (kB < P_N) {
      const float v2 = fmaxf(zzi + lpp[kB] - 2.0f * GTi[kB] +
                             TWO_EPS * (szi - lsp[kB]) + ZEPS2, 0.0f);
      if (v2 < v1) { v1 = v2; i1 = kB; }
    }
#pragma unroll
    for (int off = 1; off < 64; off <<= 1) {
      const float ov = __shfl_xor(v1, off, 64);
      const int oi = __shfl_xor(i1, off, 64);
      if (ov < v1 || (ov == v1 && oi < i1)) { v1 = ov; i1 = oi; }
    }
    const int p = i1;

    // step b: hardest positive in same-class suffix (w-gather, R6 shape)
    const float cp = lpp[p] + TWO_EPS * lsp[p] + ZEPS2;
    const int n = cnt[cls];
    const int* __restrict__ bk = bkt + cls * BCAP;
    float best = -INFINITY;
    int bestj = 0x7fffffff;
    for (int t = lane; t < n; t += 64) {
      const int jj = bk[t];
      if (jj >= i) {
        const float vv = fmaxf(cp + w[jj] - 2.0f * GT[(size_t)jj * GT_S + p], 0.0f);
        if (vv > best || (vv == best && jj < bestj)) { best = vv; bestj = jj; }
      }
    }
#pragma unroll
    for (int off = 1; off < 64; off <<= 1) {
      const float ov = __shfl_xor(best, off, 64);
      const int oj = __shfl_xor(bestj, off, 64);
      if (ov > best || (ov == best && oj < bestj)) { best = ov; bestj = oj; }
    }
    const float Dp = sqrtf(best);
    const int jp = bestj;

    // step c: logsumexp(-D_n) over proxies
    const float zzj = zz[jp], szj = sz[jp];
    const float* __restrict__ GTj = GT + (size_t)jp * GT_S;
    const float d1 = sqrtf(fmaxf(zzj + lpp[lane] - 2.0f * GTj[lane] +
                                 TWO_EPS * (szj - lsp[lane]) + ZEPS2, 0.0f));
    float d2 = INFINITY;
    if (kB < P_N)
      d2 = sqrtf(fmaxf(zzj + lpp[kB] - 2.0f * GTj[kB] +
                       TWO_EPS * (szj - lsp[kB]) + ZEPS2, 0.0f));
    const float mn = wave_min(fminf(d1, d2));
    float ss = expf(mn - d1) + ((kB < P_N) ? expf(mn - d2) : 0.0f);
    ss = wave_sum(ss);
    loss = Dp - mn + logf(ss);
  }
  if (lane == 0) part[wv] = (wid < A_N) ? loss : 0.0f;
  __syncthreads();

  // finalize (R10/R11-validated hierarchical counters)
  if (wv == 0) {
    int last = 0;
    if (lane == 0) {
      AT_ST(&partial[b], part[0] + part[1] + part[2] + part[3]);
      __builtin_amdgcn_s_waitcnt(0);       // store completed at LLC
      const int sub = b & 15;              // residues 0..10: 43; 11..15: 42
      const unsigned quota = (sub < 11) ? 43u : 42u;
      const unsigned old = AT_ADDU(&ctr[sub * 32], 1u);
      if (old == quota - 1u) {
        const unsigned so = AT_ADDU(&ctr[16 * 32], 1u);
        if (so == 15u) last = 1;
      }
    }
    last = __shfl(last, 0, 64);
    if (last) {                            // one wave reduces 683 partials
      float s = 0.0f;
#pragma unroll
      for (int r = 0; r < 11; ++r) {
        const int t = lane + r * 64;
        if (t < NPART) s += AT_LD(&partial[t]);
      }
      s = wave_sum(s);
      if (lane == 0) out[0] = s * (1.0f / (float)A_N);
    }
  }
}

extern "C" void kernel_launch(void* const* d_in, const int* in_sizes, int n_in,
                              void* d_out, int out_size, void* d_ws, size_t ws_size,
                              hipStream_t stream) {
  const float* z = (const float*)d_in[0];      // [8192,128] f32
  const int* y_idx = (const int*)d_in[1];      // [8192] i32
  const float* prox = (const float*)d_in[2];   // [93,128] f32
  const int* y_map = (const int*)d_in[3];      // [62] i32
  float* out = (float*)d_out;

  // workspace layout (bytes), ~3.31 MB
  char* ws = (char*)d_ws;
  unsigned int* ctr = (unsigned int*)(ws + 0); // 17 counters, 128B stride
  float* pp    = (float*)(ws + 2560);          // 93*4 (pad 512)
  float* sp    = (float*)(ws + 3072);          // 93*4 (pad 512) -> 3584
  float* zz    = (float*)(ws + 3584);          // 8192*4 -> 36352
  float* sz    = (float*)(ws + 36352);         // -> 69120
  float* w     = (float*)(ws + 69120);         // -> 101888
  int*   cnt   = (int*)  (ws + 101888);        // 62*4 (pad 256) -> 102144
  int*   bkt   = (int*)  (ws + 102144);        // 62*256*4 -> 165632
  float* parts = (float*)(ws + 165632);        // 683*4 (pad) -> 168448
  float* GT    = (float*)(ws + 168448);        // 8192*96*4 -> 3314176

  // MEASUREMENT ROUND: kA launched 3x (idempotent) to expose T_kA in the
  // total: dur ~= 53 + 3*T_kA + T_kB2. Delta vs R12 (81.4) = 2*T_kA.
  kA<<<256 + NCLS, 512, 0, stream>>>(z, y_idx, prox, y_map,
                                     pp, sp, zz, sz, w, cnt, bkt, GT, ctr);
  kA<<<256 + NCLS, 512, 0, stream>>>(z, y_idx, prox, y_map,
                                     pp, sp, zz, sz, w, cnt, bkt, GT, ctr);
  kA<<<256 + NCLS, 512, 0, stream>>>(z, y_idx, prox, y_map,
                                     pp, sp, zz, sz, w, cnt, bkt, GT, ctr);
  kB2<<<NPART, 256, 0, stream>>>(y_idx, y_map, pp, sp, zz, sz, w,
                                 cnt, bkt, GT, parts, ctr, out);
}

// Round 16
// 82.223 us; speedup vs baseline: 1.2912x; 1.2912x over previous
//
#include <hip/hip_runtime.h>
#include <math.h>

// Problem constants (match reference setup_inputs)
#define B_N   8192      // samples
#define Z_D   128       // feature dim
#define P_N   93        // proxies
#define NCLS  62        // classes
#define A_N   2730      // anchors: arange(0, 8189, 3)
#define BCAP  256       // class-bucket capacity (max expected ~180)
#define GT_S  96        // GT row stride
#define NPART 1365      // kB2 grid: 2 anchors/block; 1365 = 16*85 + 5
#define TWO_EPS   2e-6f
#define ZEPS2     (128.0f * 1e-6f * 1e-6f)

// Relaxed agent-scope ops: coherence-point execution, no cache maintenance
// (R5/R6/R10/R11-validated). Hierarchical counters keep RMW chains <=86 deep.
#define AT_LD(p)      __hip_atomic_load((p), __ATOMIC_RELAXED, __HIP_MEMORY_SCOPE_AGENT)
#define AT_ST(p, v)   __hip_atomic_store((p), (v), __ATOMIC_RELAXED, __HIP_MEMORY_SCOPE_AGENT)
#define AT_ADDU(p, v) __hip_atomic_fetch_add((p), (v), __ATOMIC_RELAXED, __HIP_MEMORY_SCOPE_AGENT)

__device__ __forceinline__ float wave_sum(float v) {
#pragma unroll
  for (int off = 1; off < 64; off <<= 1) v += __shfl_xor(v, off, 64);
  return v;
}
__device__ __forceinline__ float wave_min(float v) {
#pragma unroll
  for (int off = 1; off < 64; off <<= 1) v = fminf(v, __shfl_xor(v, off, 64));
  return v;
}

// --- kA: EXACT R12-benched body (318 blocks x 512 thr, 1 row/thread, LDS
// pre-scaled proxy tile). Unchanged — this round's variable is kB2 only. ----
__global__ __launch_bounds__(512) void kA(
    const float* __restrict__ z, const int* __restrict__ y_idx,
    const float* __restrict__ prox, const int* __restrict__ y_map,
    float* __restrict__ pp, float* __restrict__ sp,
    float* __restrict__ zz, float* __restrict__ sz, float* __restrict__ w,
    int* __restrict__ cnt, int* __restrict__ bkt, float* __restrict__ GT,
    unsigned int* __restrict__ ctr) {
  __shared__ float linv[6];
  __shared__ float pt[6 * Z_D];            // pre-scaled proxy tile (3 KB)
  __shared__ int lcnt;
  const int b = blockIdx.x, tid = threadIdx.x;
  const int lane = tid & 63, wv = tid >> 6;

  if (b == 0 && tid < 17) ctr[tid * 32] = 0u;  // visible to kB2 via boundary

  if (b < 256) {
    const int jch = b & 15, kt = b >> 4, k0 = kt * 6;
    const int nk = (kt == 15) ? 3 : 6;
    const int j = jch * 512 + tid;
    const float* __restrict__ zrow = z + (size_t)j * Z_D;
    if (wv < nk) {                         // per-proxy norm via wave reduce
      const int k = k0 + wv;
      const float a = prox[k * Z_D + lane];
      const float c = prox[k * Z_D + 64 + lane];
      const float s = wave_sum(a + c);
      const float q = wave_sum(a * a + c * c);
      const float inv = 1.0f / fmaxf(sqrtf(q), 1e-12f);
      if (lane == 0) {
        linv[wv] = inv;
        if (jch == 0) { pp[k] = q * inv * inv; sp[k] = s * inv; }
      }
    }
    __syncthreads();
    {
      const int nf = nk * 32;
      const float4* __restrict__ src = (const float4*)(prox + (size_t)k0 * Z_D);
      for (int t = tid; t < nf; t += 512) {
        const float iv = linv[t >> 5];
        const float4 v = src[t];
        ((float4*)pt)[t] = make_float4(v.x * iv, v.y * iv, v.z * iv, v.w * iv);
      }
    }
    __syncthreads();
    if (kt < 15) {
      float a0 = 0, a1 = 0, a2 = 0, a3 = 0, a4 = 0, a5 = 0;
#pragma unroll 8
      for (int i4 = 0; i4 < Z_D; i4 += 4) {
        const float4 zv = *(const float4*)(zrow + i4);
        const int f = i4 >> 2;
        const float4 q0 = ((const float4*)pt)[0 * 32 + f];  // LDS broadcast
        const float4 q1 = ((const float4*)pt)[1 * 32 + f];
        const float4 q2 = ((const float4*)pt)[2 * 32 + f];
        const float4 q3 = ((const float4*)pt)[3 * 32 + f];
        const float4 q4 = ((const float4*)pt)[4 * 32 + f];
        const float4 q5 = ((const float4*)pt)[5 * 32 + f];
        a0 += zv.x * q0.x + zv.y * q0.y + zv.z * q0.z + zv.w * q0.w;
        a1 += zv.x * q1.x + zv.y * q1.y + zv.z * q1.z + zv.w * q1.w;
        a2 += zv.x * q2.x + zv.y * q2.y + zv.z * q2.z + zv.w * q2.w;
        a3 += zv.x * q3.x + zv.y * q3.y + zv.z * q3.z + zv.w * q3.w;
        a4 += zv.x * q4.x + zv.y * q4.y + zv.z * q4.z + zv.w * q4.w;
        a5 += zv.x * q5.x + zv.y * q5.y + zv.z * q5.z + zv.w * q5.w;
      }
      float* g = GT + (size_t)j * GT_S + k0;       // k0 even -> 8B aligned
      *(float2*)(g + 0) = make_float2(a0, a1);
      *(float2*)(g + 2) = make_float2(a2, a3);
      *(float2*)(g + 4) = make_float2(a4, a5);
    } else {
      float a0 = 0, a1 = 0, a2 = 0, zs = 0, zq = 0;
#pragma unroll 8
      for (int i4 = 0; i4 < Z_D; i4 += 4) {
        const float4 zv = *(const float4*)(zrow + i4);
        const int f = i4 >> 2;
        const float4 q0 = ((const float4*)pt)[0 * 32 + f];
        const float4 q1 = ((const float4*)pt)[1 * 32 + f];
        const float4 q2 = ((const float4*)pt)[2 * 32 + f];
        zs += zv.x + zv.y + zv.z + zv.w;
        zq += zv.x * zv.x + zv.y * zv.y + zv.z * zv.z + zv.w * zv.w;
        a0 += zv.x * q0.x + zv.y * q0.y + zv.z * q0.z + zv.w * q0.w;
        a1 += zv.x * q1.x + zv.y * q1.y + zv.z * q1.z + zv.w * q1.w;
        a2 += zv.x * q2.x + zv.y * q2.y + zv.z * q2.z + zv.w * q2.w;
      }
      float* g = GT + (size_t)j * GT_S + 90;       // 90 even -> 8B aligned
      *(float2*)(g) = make_float2(a0, a1);
      g[2] = a2;
      zz[j] = zq;
      sz[j] = zs;
      w[j] = zq - TWO_EPS * zs;            // per-j part of pdist(prox, z)
    }
  } else {
    // --- P0: class c = b-256 compacts its sample indices (y_map unique).
    const int c = b - 256;
    if (tid == 0) lcnt = 0;
    __syncthreads();
    const int ym = y_map[c];
    for (int j = tid; j < B_N; j += 512) {
      if (y_idx[j] == ym) {
        const int pos = atomicAdd(&lcnt, 1);     // LDS atomic
        if (pos < BCAP) bkt[c * BCAP + pos] = j;
      }
    }
    __syncthreads();
    if (tid == 0) cnt[c] = min(lcnt, BCAP);
  }
}

// --- kB2: 2 anchors/block, TWO waves per anchor. All 4 bucket rounds + cnt
// prefetched before step a (no cnt->bk->gather chain); waves split even/odd
// rounds; LDS merge keeps smallest-j tie-break; even wave does step c. ------
__global__ __launch_bounds__(256) void kB2(
    const int* __restrict__ y_idx, const int* __restrict__ y_map,
    const float* __restrict__ pp, const float* __restrict__ sp,
    const float* __restrict__ zz, const float* __restrict__ sz,
    const float* __restrict__ w,
    const int* __restrict__ cnt, const int* __restrict__ bkt,
    const float* __restrict__ GT, float* partial, unsigned int* ctr,
    float* __restrict__ out) {
  __shared__ float lpp[P_N], lsp[P_N];
  __shared__ int lymap[NCLS];
  __shared__ float bw_v[4];
  __shared__ int bw_j[4];
  __shared__ float part[2];
  const int b = blockIdx.x;
  const int tid = threadIdx.x, lane = tid & 63, wv = tid >> 6;
  const int pair = wv >> 1, half = wv & 1;
  if (tid < P_N) { lpp[tid] = pp[tid]; lsp[tid] = sp[tid]; }
  if (tid < NCLS) lymap[tid] = y_map[tid];
  __syncthreads();

  const int wid = b * 2 + pair;            // 1365*2 = 2730 exactly, no tail
  const int i = 3 * wid;
  const int yi = y_idx[i];
  const unsigned long long mm = __ballot(lane < NCLS && lymap[lane] == yi);
  const int cls = __ffsll(mm) - 1;         // unique match (y_map unique)
  const int* __restrict__ bk = bkt + cls * BCAP;

  // PREFETCH: cnt + this wave's two bucket rounds issue NOW, overlapping
  // step a. Entries past cnt are 0xAA poison -> clamped below, compare
  // predicated on t<n.
  const int n = cnt[cls];
  const int t0 = half * 64 + lane, t1 = t0 + 128;  // rounds {0,2} / {1,3}
  const int e0 = bk[t0], e1 = bk[t1];
  const float zzi = zz[i], szi = sz[i];
  const int kB = lane + 64;

  // step a (computed redundantly by both halves; identical results)
  const float* __restrict__ GTi = GT + (size_t)i * GT_S;
  float v1 = fmaxf(zzi + lpp[lane] - 2.0f * GTi[lane] +
                   TWO_EPS * (szi - lsp[lane]) + ZEPS2, 0.0f);
  int i1 = lane;
  if (kB < P_N) {
    const float v2 = fmaxf(zzi + lpp[kB] - 2.0f * GTi[kB] +
                           TWO_EPS * (szi - lsp[kB]) + ZEPS2, 0.0f);
    if (v2 < v1) { v1 = v2; i1 = kB; }
  }
#pragma unroll
  for (int off = 1; off < 64; off <<= 1) {
    const float ov = __shfl_xor(v1, off, 64);
    const int oi = __shfl_xor(i1, off, 64);
    if (ov < v1 || (ov == v1 && oi < i1)) { v1 = ov; i1 = oi; }
  }
  const int p = i1;

  // step b (this wave's half): clamped gathers, predicated compare
  const float cp = lpp[p] + TWO_EPS * lsp[p] + ZEPS2;
  const bool a0ok = (t0 < n) && (e0 >= i);
  const bool a1ok = (t1 < n) && (e1 >= i);
  const int r0 = a0ok ? e0 : i;            // i is always a valid row
  const int r1 = a1ok ? e1 : i;
  const float w0 = w[r0], g0 = GT[(size_t)r0 * GT_S + p];
  const float w1 = w[r1], g1 = GT[(size_t)r1 * GT_S + p];
  float best = -INFINITY;
  int bestj = 0x7fffffff;
  if (a0ok) { best = fmaxf(cp + w0 - 2.0f * g0, 0.0f); bestj = e0; }
  if (a1ok) {
    const float vv = fmaxf(cp + w1 - 2.0f * g1, 0.0f);
    if (vv > best || (vv == best && e1 < bestj)) { best = vv; bestj = e1; }
  }
#pragma unroll
  for (int off = 1; off < 64; off <<= 1) {
    const float ov = __shfl_xor(best, off, 64);
    const int oj = __shfl_xor(bestj, off, 64);
    if (ov > best || (ov == best && oj < bestj)) { best = ov; bestj = oj; }
  }
  if (lane == 0) { bw_v[wv] = best; bw_j[wv] = bestj; }
  __syncthreads();

  // merge the two halves + step c (even wave of the pair only)
  if (half == 0) {
    float bA = bw_v[wv], bB = bw_v[wv + 1];
    int jA = bw_j[wv], jB = bw_j[wv + 1];
    if (bB > bA || (bB == bA && jB < jA)) { bA = bB; jA = jB; }
    const float Dp = sqrtf(bA);
    const int jp = jA;                     // row i always qualifies => valid

    const float zzj = zz[jp], szj = sz[jp];
    const float* __restrict__ GTj = GT + (size_t)jp * GT_S;
    const float d1 = sqrtf(fmaxf(zzj + lpp[lane] - 2.0f * GTj[lane] +
                                 TWO_EPS * (szj - lsp[lane]) + ZEPS2, 0.0f));
    float d2 = INFINITY;
    if (kB < P_N)
      d2 = sqrtf(fmaxf(zzj + lpp[kB] - 2.0f * GTj[kB] +
                       TWO_EPS * (szj - lsp[kB]) + ZEPS2, 0.0f));
    const float mn = wave_min(fminf(d1, d2));
    float ss = expf(mn - d1) + ((kB < P_N) ? expf(mn - d2) : 0.0f);
    ss = wave_sum(ss);
    if (lane == 0) part[pair] = Dp - mn + logf(ss);
  }
  __syncthreads();

  // finalize (R10/R11-validated hierarchical counters, 1365 = 16*85 + 5)
  if (wv == 0) {
    int last = 0;
    if (lane == 0) {
      AT_ST(&partial[b], part[0] + part[1]);
      __builtin_amdgcn_s_waitcnt(0);       // store completed at LLC
      const int sub = b & 15;              // residues 0..4: 86; 5..15: 85
      const unsigned quota = (sub < 5) ? 86u : 85u;
      const unsigned old = AT_ADDU(&ctr[sub * 32], 1u);
      if (old == quota - 1u) {
        const unsigned so = AT_ADDU(&ctr[16 * 32], 1u);
        if (so == 15u) last = 1;
      }
    }
    last = __shfl(last, 0, 64);
    if (last) {                            // one wave reduces 1365 partials
      float s = 0.0f;
      for (int r = 0; r < 22; ++r) {
        const int t = lane + r * 64;
        if (t < NPART) s += AT_LD(&partial[t]);
      }
      s = wave_sum(s);
      if (lane == 0) out[0] = s * (1.0f / (float)A_N);
    }
  }
}

extern "C" void kernel_launch(void* const* d_in, const int* in_sizes, int n_in,
                              void* d_out, int out_size, void* d_ws, size_t ws_size,
                              hipStream_t stream) {
  const float* z = (const float*)d_in[0];      // [8192,128] f32
  const int* y_idx = (const int*)d_in[1];      // [8192] i32
  const float* prox = (const float*)d_in[2];   // [93,128] f32
  const int* y_map = (const int*)d_in[3];      // [62] i32
  float* out = (float*)d_out;

  // workspace layout (bytes), ~3.32 MB
  char* ws = (char*)d_ws;
  unsigned int* ctr = (unsigned int*)(ws + 0); // 17 counters, 128B stride
  float* pp    = (float*)(ws + 2560);          // 93*4 (pad 512)
  float* sp    = (float*)(ws + 3072);          // 93*4 (pad 512) -> 3584
  float* zz    = (float*)(ws + 3584);          // 8192*4 -> 36352
  float* sz    = (float*)(ws + 36352);         // -> 69120
  float* w     = (float*)(ws + 69120);         // -> 101888
  int*   cnt   = (int*)  (ws + 101888);        // 62*4 (pad 256) -> 102144
  int*   bkt   = (int*)  (ws + 102144);        // 62*256*4 -> 165632
  float* parts = (float*)(ws + 165632);        // 1365*4 (pad) -> 171136
  float* GT    = (float*)(ws + 171136);        // 8192*96*4 -> 3316864

  kA<<<256 + NCLS, 512, 0, stream>>>(z, y_idx, prox, y_map,
                                     pp, sp, zz, sz, w, cnt, bkt, GT, ctr);
  kB2<<<NPART, 256, 0, stream>>>(y_idx, y_map, pp, sp, zz, sz, w,
                                 cnt, bkt, GT, parts, ctr, out);
}